// Round 13
// baseline (665.294 us; speedup 1.0000x reference)
//
#include <hip/hip_runtime.h>
#include <math.h>

#define NSEQ 430
#define SEQL 25
#define EMB  20
#define SVS  10
#define NH   5
#define FFND 10
#define NL   4
#define BB   32           // batch used as sequence axis (S)
#define NTA  256          // kernel A: 4 waves, 8 halfwaves = 8 columns
#define BPI  4            // blocks per index i (8+8+8+1 columns)
#define NTB  320          // kernel B threads

__device__ __forceinline__ void cp_lds(float* dst, const float* src, int n, int tid, int nt) {
    for (int k = tid; k < n; k += nt) dst[k] = src[k];
}

// dot of 20 per-lane values with an LDS row (5x ds_read_b128, broadcast, imm offsets)
__device__ __forceinline__ float dot20L(const float* x, const float4* w4, float acc) {
#pragma unroll
    for (int j = 0; j < 5; ++j) {
        float4 wv = w4[j];
        acc = fmaf(x[4*j+0], wv.x, acc);
        acc = fmaf(x[4*j+1], wv.y, acc);
        acc = fmaf(x[4*j+2], wv.z, acc);
        acc = fmaf(x[4*j+3], wv.w, acc);
    }
    return acc;
}

template<int N>
__device__ __forceinline__ void ln_vec(float* v, const float* g, const float* b) {
    float m = 0.f;
#pragma unroll
    for (int e = 0; e < N; e++) m += v[e];
    m *= (1.0f / N);
    float var = 0.f;
#pragma unroll
    for (int e = 0; e < N; e++) { float d = v[e] - m; var = fmaf(d, d, var); }
    var *= (1.0f / N);
    float rs = rsqrtf(var + 1e-5f);
#pragma unroll
    for (int e = 0; e < N; e++) v[e] = (v[e] - m) * rs * g[e] + b[e];
}

// ---------------- kernel A: pt-encoder, column-parallel, LDS weights ----------
__global__ void __launch_bounds__(NTA)
ptenc_kernel(const float* __restrict__ X,
             const float* __restrict__ Wqkv, const float* __restrict__ bqkv,
             const float* __restrict__ Wo,   const float* __restrict__ bo,
             const float* __restrict__ W1,   const float* __restrict__ b1,
             const float* __restrict__ W2,   const float* __restrict__ b2,
             const float* __restrict__ g1,   const float* __restrict__ be1,
             const float* __restrict__ g2,   const float* __restrict__ be2,
             const float* __restrict__ linW,
             float* __restrict__ part)
{
    __shared__ __align__(16) float pool[8 * BB * 12];   // 12288 B K/V staging, stride 12
    __shared__ __align__(16) float pWqkv[1200];         // per-layer weights (8.8 KB)
    __shared__ __align__(16) float pWo[400];
    __shared__ __align__(16) float pW1[200];
    __shared__ __align__(16) float pW2[200];
    __shared__ __align__(16) float pbqkv[60];
    __shared__ __align__(16) float pbo[20];
    __shared__ __align__(16) float pb1[10];
    __shared__ __align__(16) float pb2[20];
    __shared__ __align__(16) float pg1[20], pbe1[20], pg2[20], pbe2[20];

    const int bid = blockIdx.x;
    const int i   = bid >> 2;          // index
    const int blk = bid & 3;           // column-block 0..3
    const int tid = threadIdx.x;
    const int hw  = tid >> 5;          // 0..7
    const int s   = tid & 31;
    const int col = blk * 8 + hw;      // 0..31
    const bool act = (col < SEQL);

    float x[20];
    if (act) {
        const float4* xr4 = (const float4*)(X + (((size_t)s * NSEQ + i) * SEQL + col) * EMB);
#pragma unroll
        for (int j = 0; j < 5; ++j) {
            float4 t4 = xr4[j];
            x[4*j+0] = t4.x; x[4*j+1] = t4.y; x[4*j+2] = t4.z; x[4*j+3] = t4.w;
        }
#pragma unroll
        for (int j = 0; j < 10; ++j) {
            float div = expf(-0.9210340371976184f * (float)j); // 10000^(-j/10)
            float ang = (float)s * div;
            x[2*j]   += sinf(ang);
            x[2*j+1] += cosf(ang);
        }
    }

    float4* my4 = (float4*)&pool[(hw * BB + s) * 12];
    const float4* kvr4 = (const float4*)&pool[hw * BB * 12];

#pragma unroll 1
    for (int l = 0; l < NL; ++l) {
        __syncthreads();   // previous layer done reading weights
        const size_t po = (size_t)i * NL + l;
        cp_lds(pWqkv, Wqkv + po * 1200, 1200, tid, NTA);
        cp_lds(pbqkv, bqkv + po * 60,   60,   tid, NTA);
        cp_lds(pWo,   Wo   + po * 400,  400,  tid, NTA);
        cp_lds(pbo,   bo   + po * 20,   20,   tid, NTA);
        cp_lds(pW1,   W1   + po * 200,  200,  tid, NTA);
        cp_lds(pb1,   b1   + po * 10,   10,   tid, NTA);
        cp_lds(pW2,   W2   + po * 200,  200,  tid, NTA);
        cp_lds(pb2,   b2   + po * 20,   20,   tid, NTA);
        cp_lds(pg1,   g1   + po * 20,   20,   tid, NTA);
        cp_lds(pbe1,  be1  + po * 20,   20,   tid, NTA);
        cp_lds(pg2,   g2   + po * 20,   20,   tid, NTA);
        cp_lds(pbe2,  be2  + po * 20,   20,   tid, NTA);
        __syncthreads();

        if (act) {
            float out[20];
#pragma unroll
            for (int h = 0; h < NH; ++h) {
                float q[4], k[4], v[4];
#pragma unroll
                for (int d = 0; d < 4; ++d) {
                    const int f = h * 4 + d;   // compile-time after unroll -> imm offsets
                    q[d] = dot20L(x, (const float4*)&pWqkv[f * EMB],        pbqkv[f]);
                    k[d] = dot20L(x, (const float4*)&pWqkv[(20 + f) * EMB], pbqkv[20 + f]);
                    v[d] = dot20L(x, (const float4*)&pWqkv[(40 + f) * EMB], pbqkv[40 + f]);
                    q[d] *= 0.72134752044f;    // 0.5 (1/sqrt D) * log2(e)
                }
                // stage k,v (same-wave in-order LDS within a halfwave: no barrier)
                my4[0] = make_float4(k[0], k[1], k[2], k[3]);
                my4[1] = make_float4(v[0], v[1], v[2], v[3]);
                float den = 0.f, o0 = 0.f, o1 = 0.f, o2 = 0.f, o3 = 0.f;
#pragma unroll 4
                for (int t = 0; t < BB; ++t) {
                    float4 kt = kvr4[t * 3 + 0];
                    float4 vt = kvr4[t * 3 + 1];
                    float sc = fmaf(q[0], kt.x, fmaf(q[1], kt.y, fmaf(q[2], kt.z, q[3] * kt.w)));
                    float p = exp2f(sc);
                    den += p;
                    o0 = fmaf(p, vt.x, o0);
                    o1 = fmaf(p, vt.y, o1);
                    o2 = fmaf(p, vt.z, o2);
                    o3 = fmaf(p, vt.w, o3);
                }
                float inv = 1.0f / den;
                out[4*h+0] = o0 * inv;
                out[4*h+1] = o1 * inv;
                out[4*h+2] = o2 * inv;
                out[4*h+3] = o3 * inv;
            }
            float cr[20];
#pragma unroll
            for (int e = 0; e < 20; ++e)
                cr[e] = x[e] + dot20L(out, (const float4*)&pWo[e * EMB], pbo[e]);
            ln_vec<20>(cr, pg1, pbe1);
            float hb[FFND];
#pragma unroll
            for (int j = 0; j < FFND; ++j)
                hb[j] = fmaxf(dot20L(cr, (const float4*)&pW1[j * EMB], pb1[j]), 0.f);
#pragma unroll
            for (int e = 0; e < 20; ++e) {
                const float2* w2 = (const float2*)&pW2[e * FFND];  // 8B-aligned
                float acc = pb2[e];
#pragma unroll
                for (int m = 0; m < 5; ++m) {
                    float2 wv = w2[m];
                    acc = fmaf(hb[2*m],   wv.x, acc);
                    acc = fmaf(hb[2*m+1], wv.y, acc);
                }
                x[e] = cr[e] + acc;
            }
            ln_vec<20>(x, pg2, pbe2);
        }
    }

    // lin partials for this column into pool (per-lane-owned slots; wave-lockstep safe)
    if (act) {
        const float* lwb = linW + (size_t)i * SVS * (SEQL * EMB);
        float* slot = &pool[(hw * BB + s) * 12];
#pragma unroll
        for (int o = 0; o < SVS; ++o) {
            const float* wr = lwb + o * (SEQL * EMB) + col * EMB;
            float acc = 0.f;
#pragma unroll
            for (int j = 0; j < 20; ++j) acc = fmaf(x[j], wr[j], acc);
            slot[o] = acc;
        }
    }
    __syncthreads();

    // block-reduce the (≤8) active columns -> part[i][blk][b][o]  (strided: 320 > 256)
    for (int idx = tid; idx < BB * SVS; idx += NTA) {
        const int b = idx / SVS, o = idx % SVS;
        const int ncols = (blk == 3) ? 1 : 8;
        float acc = 0.f;
        for (int c = 0; c < ncols; ++c) acc += pool[(c * BB + b) * 12 + o];
        part[(((size_t)i * BPI + blk) * BB + b) * SVS + o] = acc;
    }
}

// ---------------- kernel B: lin-bias + st-encoder ----------------
__global__ void __launch_bounds__(NTB)
stenc_kernel(const float* __restrict__ part, const float* __restrict__ linb,
             const float* __restrict__ sWqkv,const float* __restrict__ sbqkv,
             const float* __restrict__ sWo,  const float* __restrict__ sbo,
             const float* __restrict__ sW1,  const float* __restrict__ sb1,
             const float* __restrict__ sW2,  const float* __restrict__ sb2,
             const float* __restrict__ sg1,  const float* __restrict__ sbe1,
             const float* __restrict__ sg2,  const float* __restrict__ sbe2,
             float* __restrict__ sec)
{
    __shared__ float stx[BB][SVS];
    __shared__ float stqkv[BB][3*SVS];
    __shared__ float sttmp[BB][SVS];
    __shared__ float pqW[300], pqB[30], poW[100], poB[10];
    __shared__ float p1W[100], p1B[10], p2W[100], p2B[10];
    __shared__ float pg1[10], pbe1[10], pg2[10], pbe2[10];

    const int i   = blockIdx.x;
    const int tid = threadIdx.x;

    if (tid < BB * SVS) {
        const int b = tid / SVS, o = tid % SVS;
        float acc = linb[i * SVS + o];
#pragma unroll
        for (int blk = 0; blk < BPI; ++blk)
            acc += part[(((size_t)i * BPI + blk) * BB + b) * SVS + o];
        stx[b][o] = acc;
    }

#pragma unroll 1
    for (int l = 0; l < NL; ++l) {
        __syncthreads();
        cp_lds(pqW, sWqkv + l * 300, 300, tid, NTB);
        cp_lds(pqB, sbqkv + l * 30,  30,  tid, NTB);
        cp_lds(poW, sWo   + l * 100, 100, tid, NTB);
        cp_lds(poB, sbo   + l * 10,  10,  tid, NTB);
        cp_lds(p1W, sW1   + l * 100, 100, tid, NTB);
        cp_lds(p1B, sb1   + l * 10,  10,  tid, NTB);
        cp_lds(p2W, sW2   + l * 100, 100, tid, NTB);
        cp_lds(p2B, sb2   + l * 10,  10,  tid, NTB);
        cp_lds(pg1, sg1   + l * 10,  10,  tid, NTB);
        cp_lds(pbe1, sbe1 + l * 10,  10,  tid, NTB);
        cp_lds(pg2, sg2   + l * 10,  10,  tid, NTB);
        cp_lds(pbe2, sbe2 + l * 10,  10,  tid, NTB);
        __syncthreads();

        for (int idx = tid; idx < BB * 3 * SVS; idx += NTB) {   // 960 dots, len 10
            int s2 = idx / (3 * SVS), f = idx % (3 * SVS);
            float acc = pqB[f];
#pragma unroll
            for (int e = 0; e < SVS; e++) acc = fmaf(stx[s2][e], pqW[f * SVS + e], acc);
            stqkv[s2][f] = acc;
        }
        __syncthreads();

        if (tid < BB * NH) {       // attention per (s, h), D=2; single pass
            int s2 = tid / NH, h = tid % NH;
            float q0 = stqkv[s2][h * 2], q1 = stqkv[s2][h * 2 + 1];
            float den = 0.f, o0 = 0.f, o1 = 0.f;
#pragma unroll
            for (int t = 0; t < BB; t++) {
                float d0 = q0 * stqkv[t][SVS + h * 2] + q1 * stqkv[t][SVS + h * 2 + 1];
                float p = __expf(0.70710678118f * d0);
                den += p;
                o0 = fmaf(p, stqkv[t][2 * SVS + h * 2],     o0);
                o1 = fmaf(p, stqkv[t][2 * SVS + h * 2 + 1], o1);
            }
            float inv = 1.0f / den;
            sttmp[s2][h * 2]     = o0 * inv;
            sttmp[s2][h * 2 + 1] = o1 * inv;
        }
        __syncthreads();

        if (tid < BB) {            // proj + LN1 + FFN + LN2, token-local
            int s2 = tid;
            float cr[SVS];
#pragma unroll
            for (int e = 0; e < SVS; e++) {
                float acc = poB[e];
#pragma unroll
                for (int f = 0; f < SVS; f++) acc = fmaf(sttmp[s2][f], poW[e * SVS + f], acc);
                cr[e] = stx[s2][e] + acc;
            }
            ln_vec<SVS>(cr, pg1, pbe1);
            float hb[FFND];
#pragma unroll
            for (int j = 0; j < FFND; j++) {
                float acc = p1B[j];
#pragma unroll
                for (int e = 0; e < SVS; e++) acc = fmaf(cr[e], p1W[j * SVS + e], acc);
                hb[j] = fmaxf(acc, 0.f);
            }
            float fr[SVS];
#pragma unroll
            for (int e = 0; e < SVS; e++) {
                float acc = p2B[e];
#pragma unroll
                for (int j = 0; j < FFND; j++) acc = fmaf(hb[j], p2W[e * FFND + j], acc);
                fr[e] = cr[e] + acc;
            }
            ln_vec<SVS>(fr, pg2, pbe2);
#pragma unroll
            for (int e = 0; e < SVS; e++) stx[s2][e] = fr[e];
        }
        __syncthreads();
    }

    if (tid < BB * SVS) {
        int b = tid / SVS, o = tid % SVS;
        sec[(size_t)b * (NSEQ * SVS) + (size_t)i * SVS + o] = stx[b][o];
    }
}

__global__ __launch_bounds__(256, 1)
void head_kernel(const float* __restrict__ sec,
                 const float* __restrict__ plW, const float* __restrict__ plb,
                 const float* __restrict__ llW, const float* __restrict__ llb,
                 float* __restrict__ out)
{
    const int b = blockIdx.x, tid = threadIdx.x;
    const float* fb = sec + (size_t)b * (NSEQ * SVS);
    float acc[8];
#pragma unroll
    for (int p = 0; p < 8; p++) acc[p] = 0.f;
    for (int f = tid; f < NSEQ * SVS; f += 256) {
        float xv = fb[f];
#pragma unroll
        for (int p = 0; p < 8; p++)
            acc[p] = fmaf(xv, plW[p * (NSEQ * SVS) + f], acc[p]);
    }
#pragma unroll
    for (int p = 0; p < 8; p++) {
#pragma unroll
        for (int off = 32; off > 0; off >>= 1)
            acc[p] += __shfl_down(acc[p], off, 64);
    }
    __shared__ float red[4][8];
    const int wv = tid >> 6, ln = tid & 63;
    if (ln == 0) {
#pragma unroll
        for (int p = 0; p < 8; p++) red[wv][p] = acc[p];
    }
    __syncthreads();
    if (tid == 0) {
        float s8[8];
#pragma unroll
        for (int p = 0; p < 8; p++)
            s8[p] = red[0][p] + red[1][p] + red[2][p] + red[3][p] + plb[p];
#pragma unroll
        for (int qq = 0; qq < 2; qq++) {
            float o = llb[qq];
#pragma unroll
            for (int p = 0; p < 8; p++) o = fmaf(s8[p], llW[qq * 8 + p], o);
            out[b * 2 + qq] = o;
        }
    }
}

extern "C" void kernel_launch(void* const* d_in, const int* in_sizes, int n_in,
                              void* d_out, int out_size, void* d_ws, size_t ws_size,
                              hipStream_t stream)
{
    const float* X     = (const float*)d_in[0];
    const float* Wqkv  = (const float*)d_in[1];
    const float* bqkv  = (const float*)d_in[2];
    const float* Wo    = (const float*)d_in[3];
    const float* bo    = (const float*)d_in[4];
    const float* W1    = (const float*)d_in[5];
    const float* b1    = (const float*)d_in[6];
    const float* W2    = (const float*)d_in[7];
    const float* b2    = (const float*)d_in[8];
    const float* g1    = (const float*)d_in[9];
    const float* be1   = (const float*)d_in[10];
    const float* g2    = (const float*)d_in[11];
    const float* be2   = (const float*)d_in[12];
    const float* linW  = (const float*)d_in[13];
    const float* linb  = (const float*)d_in[14];
    const float* sWqkv = (const float*)d_in[15];
    const float* sbqkv = (const float*)d_in[16];
    const float* sWo   = (const float*)d_in[17];
    const float* sbo   = (const float*)d_in[18];
    const float* sW1   = (const float*)d_in[19];
    const float* sb1   = (const float*)d_in[20];
    const float* sW2   = (const float*)d_in[21];
    const float* sb2   = (const float*)d_in[22];
    const float* sg1   = (const float*)d_in[23];
    const float* sbe1  = (const float*)d_in[24];
    const float* sg2   = (const float*)d_in[25];
    const float* sbe2  = (const float*)d_in[26];
    const float* plW   = (const float*)d_in[27];
    const float* plb   = (const float*)d_in[28];
    const float* llW   = (const float*)d_in[29];
    const float* llb   = (const float*)d_in[30];

    float* part = (float*)d_ws;                         // 430*4*32*10 fp32 = 2,201,600 B
    float* sec  = part + (size_t)NSEQ * BPI * BB * SVS; // 550,400 B more

    ptenc_kernel<<<NSEQ * BPI, NTA, 0, stream>>>(X, Wqkv, bqkv, Wo, bo, W1, b1, W2, b2,
                                                 g1, be1, g2, be2, linW, part);
    stenc_kernel<<<NSEQ, NTB, 0, stream>>>(part, linb,
                                           sWqkv, sbqkv, sWo, sbo, sW1, sb1, sW2, sb2,
                                           sg1, sbe1, sg2, sbe2, sec);
    head_kernel<<<BB, 256, 0, stream>>>(sec, plW, plb, llW, llb, (float*)d_out);
}

// Round 14
// 346.209 us; speedup vs baseline: 1.9217x; 1.9217x over previous
//
#include <hip/hip_runtime.h>
#include <math.h>

#define NSEQ 430
#define SEQL 25
#define EMB  20
#define SVS  10
#define NH   5
#define FFND 10
#define NL   4
#define BB   32           // batch used as sequence axis (S)
#define NTA  128          // kernel A: 2 waves, 4 halfwaves = 4 columns
#define HWA  4            // columns per block
#define BPI  7            // blocks per index i (6x4 + 1 columns)
#define NTB  320          // kernel B threads

__device__ __forceinline__ void cp_lds(float* dst, const float* src, int n, int tid, int nt) {
    for (int k = tid; k < n; k += nt) dst[k] = src[k];
}

// dot of 20 per-lane values with a WAVE-UNIFORM global weight row (s_load path)
__device__ __forceinline__ float dot20g(const float* x, const float* __restrict__ w, float acc) {
#pragma unroll
    for (int j = 0; j < 20; ++j) acc = fmaf(x[j], w[j], acc);
    return acc;
}

template<int N>
__device__ __forceinline__ void ln_vec(float* v, const float* __restrict__ g,
                                       const float* __restrict__ b) {
    float m = 0.f;
#pragma unroll
    for (int e = 0; e < N; e++) m += v[e];
    m *= (1.0f / N);
    float var = 0.f;
#pragma unroll
    for (int e = 0; e < N; e++) { float d = v[e] - m; var = fmaf(d, d, var); }
    var *= (1.0f / N);
    float rs = rsqrtf(var + 1e-5f);
#pragma unroll
    for (int e = 0; e < N; e++) v[e] = (v[e] - m) * rs * g[e] + b[e];
}

// ---------------- kernel A: pt-encoder, column-parallel, 2-wave blocks --------
__global__ void __launch_bounds__(NTA)
ptenc_kernel(const float* __restrict__ X,
             const float* __restrict__ Wqkv, const float* __restrict__ bqkv,
             const float* __restrict__ Wo,   const float* __restrict__ bo,
             const float* __restrict__ W1,   const float* __restrict__ b1,
             const float* __restrict__ W2,   const float* __restrict__ b2,
             const float* __restrict__ g1,   const float* __restrict__ be1,
             const float* __restrict__ g2,   const float* __restrict__ be2,
             const float* __restrict__ linW,
             float* __restrict__ part)
{
    __shared__ __align__(16) float pool[HWA * BB * 12];   // 6144 B

    const int bid = blockIdx.x;
    const int i   = bid / BPI;         // index
    const int blk = bid % BPI;         // column-block 0..6
    const int tid = threadIdx.x;
    const int hw  = tid >> 5;          // 0..3
    const int s   = tid & 31;
    const int col = blk * HWA + hw;    // 0..27
    const bool act = (col < SEQL);

    float x[20];
    if (act) {
        const float4* xr4 = (const float4*)(X + (((size_t)s * NSEQ + i) * SEQL + col) * EMB);
#pragma unroll
        for (int j = 0; j < 5; ++j) {
            float4 t4 = xr4[j];
            x[4*j+0] = t4.x; x[4*j+1] = t4.y; x[4*j+2] = t4.z; x[4*j+3] = t4.w;
        }
#pragma unroll
        for (int j = 0; j < 10; ++j) {
            float div = expf(-0.9210340371976184f * (float)j); // 10000^(-j/10)
            float ang = (float)s * div;
            x[2*j]   += sinf(ang);
            x[2*j+1] += cosf(ang);
        }

        float4* my4 = (float4*)&pool[(hw * BB + s) * 12];
        const float4* kvr4 = (const float4*)&pool[hw * BB * 12];

#pragma unroll 1
        for (int l = 0; l < NL; ++l) {
            const size_t po = (size_t)i * NL + l;
            const float* Wq  = Wqkv + po * 1200;
            const float* bq  = bqkv + po * 60;
            const float* Wog = Wo   + po * 400;
            const float* bog = bo   + po * 20;
            const float* W1g = W1   + po * 200;
            const float* b1g = b1   + po * 10;
            const float* W2g = W2   + po * 200;
            const float* b2g = b2   + po * 20;
            const float* g1g = g1   + po * 20;
            const float* e1g = be1  + po * 20;
            const float* g2g = g2   + po * 20;
            const float* e2g = be2  + po * 20;

            float out[20];
#pragma unroll
            for (int h = 0; h < NH; ++h) {
                float q[4], k[4], v[4];
#pragma unroll
                for (int d = 0; d < 4; ++d) {
                    const int f = h * 4 + d;
                    q[d] = dot20g(x, Wq + f * 20,        bq[f]) * 0.72134752044f; // 0.5*log2e
                    k[d] = dot20g(x, Wq + (20 + f) * 20, bq[20 + f]);
                    v[d] = dot20g(x, Wq + (40 + f) * 20, bq[40 + f]);
                }
                // stage k,v (same-wave in-order LDS within a halfwave: no barrier)
                my4[0] = make_float4(k[0], k[1], k[2], k[3]);
                my4[1] = make_float4(v[0], v[1], v[2], v[3]);
                float den = 0.f, o0 = 0.f, o1 = 0.f, o2 = 0.f, o3 = 0.f;
#pragma unroll 4
                for (int t = 0; t < BB; ++t) {
                    float4 kt = kvr4[t * 3 + 0];
                    float4 vt = kvr4[t * 3 + 1];
                    float sc = fmaf(q[0], kt.x, fmaf(q[1], kt.y, fmaf(q[2], kt.z, q[3] * kt.w)));
                    float p = exp2f(sc);
                    den += p;
                    o0 = fmaf(p, vt.x, o0);
                    o1 = fmaf(p, vt.y, o1);
                    o2 = fmaf(p, vt.z, o2);
                    o3 = fmaf(p, vt.w, o3);
                }
                float inv = 1.0f / den;
                out[4*h+0] = o0 * inv;
                out[4*h+1] = o1 * inv;
                out[4*h+2] = o2 * inv;
                out[4*h+3] = o3 * inv;
            }
            float cr[20];
#pragma unroll
            for (int e = 0; e < 20; ++e)
                cr[e] = x[e] + dot20g(out, Wog + e * 20, bog[e]);
            ln_vec<20>(cr, g1g, e1g);
            float hb[FFND];
#pragma unroll
            for (int j = 0; j < FFND; ++j)
                hb[j] = fmaxf(dot20g(cr, W1g + j * 20, b1g[j]), 0.f);
#pragma unroll
            for (int e = 0; e < 20; ++e) {
                const float* w2 = W2g + e * FFND;
                float acc = b2g[e];
#pragma unroll
                for (int m = 0; m < FFND; ++m) acc = fmaf(hb[m], w2[m], acc);
                x[e] = cr[e] + acc;
            }
            ln_vec<20>(x, g2g, e2g);
        }

        // lin partials for this column into pool (per-lane-owned slots)
        const float* lwb = linW + (size_t)i * SVS * (SEQL * EMB);
        float* slot = &pool[(hw * BB + s) * 12];
#pragma unroll
        for (int o = 0; o < SVS; ++o) {
            const float* wr = lwb + o * (SEQL * EMB) + col * EMB;
            float acc = 0.f;
#pragma unroll
            for (int j = 0; j < 20; ++j) acc = fmaf(x[j], wr[j], acc);
            slot[o] = acc;
        }
    }
    __syncthreads();

    // block-reduce the (≤4) active columns -> part[i][blk][b][o] (strided: 320 > 128)
    const int ncols = (blk == BPI - 1) ? 1 : HWA;
    for (int idx = tid; idx < BB * SVS; idx += NTA) {
        const int b = idx / SVS, o = idx % SVS;
        float acc = 0.f;
        for (int c = 0; c < ncols; ++c) acc += pool[(c * BB + b) * 12 + o];
        part[(((size_t)i * BPI + blk) * BB + b) * SVS + o] = acc;
    }
}

// ---------------- kernel B: lin-bias + st-encoder ----------------
__global__ void __launch_bounds__(NTB)
stenc_kernel(const float* __restrict__ part, const float* __restrict__ linb,
             const float* __restrict__ sWqkv,const float* __restrict__ sbqkv,
             const float* __restrict__ sWo,  const float* __restrict__ sbo,
             const float* __restrict__ sW1,  const float* __restrict__ sb1,
             const float* __restrict__ sW2,  const float* __restrict__ sb2,
             const float* __restrict__ sg1,  const float* __restrict__ sbe1,
             const float* __restrict__ sg2,  const float* __restrict__ sbe2,
             float* __restrict__ sec)
{
    __shared__ float stx[BB][SVS];
    __shared__ float stqkv[BB][3*SVS];
    __shared__ float sttmp[BB][SVS];
    __shared__ float pqW[300], pqB[30], poW[100], poB[10];
    __shared__ float p1W[100], p1B[10], p2W[100], p2B[10];
    __shared__ float pg1[10], pbe1[10], pg2[10], pbe2[10];

    const int i   = blockIdx.x;
    const int tid = threadIdx.x;

    if (tid < BB * SVS) {
        const int b = tid / SVS, o = tid % SVS;
        float acc = linb[i * SVS + o];
#pragma unroll
        for (int blk = 0; blk < BPI; ++blk)
            acc += part[(((size_t)i * BPI + blk) * BB + b) * SVS + o];
        stx[b][o] = acc;
    }

#pragma unroll 1
    for (int l = 0; l < NL; ++l) {
        __syncthreads();
        cp_lds(pqW, sWqkv + l * 300, 300, tid, NTB);
        cp_lds(pqB, sbqkv + l * 30,  30,  tid, NTB);
        cp_lds(poW, sWo   + l * 100, 100, tid, NTB);
        cp_lds(poB, sbo   + l * 10,  10,  tid, NTB);
        cp_lds(p1W, sW1   + l * 100, 100, tid, NTB);
        cp_lds(p1B, sb1   + l * 10,  10,  tid, NTB);
        cp_lds(p2W, sW2   + l * 100, 100, tid, NTB);
        cp_lds(p2B, sb2   + l * 10,  10,  tid, NTB);
        cp_lds(pg1, sg1   + l * 10,  10,  tid, NTB);
        cp_lds(pbe1, sbe1 + l * 10,  10,  tid, NTB);
        cp_lds(pg2, sg2   + l * 10,  10,  tid, NTB);
        cp_lds(pbe2, sbe2 + l * 10,  10,  tid, NTB);
        __syncthreads();

        for (int idx = tid; idx < BB * 3 * SVS; idx += NTB) {   // 960 dots, len 10
            int s2 = idx / (3 * SVS), f = idx % (3 * SVS);
            float acc = pqB[f];
#pragma unroll
            for (int e = 0; e < SVS; e++) acc = fmaf(stx[s2][e], pqW[f * SVS + e], acc);
            stqkv[s2][f] = acc;
        }
        __syncthreads();

        if (tid < BB * NH) {       // attention per (s, h), D=2; single pass
            int s2 = tid / NH, h = tid % NH;
            float q0 = stqkv[s2][h * 2], q1 = stqkv[s2][h * 2 + 1];
            float den = 0.f, o0 = 0.f, o1 = 0.f;
#pragma unroll
            for (int t = 0; t < BB; t++) {
                float d0 = q0 * stqkv[t][SVS + h * 2] + q1 * stqkv[t][SVS + h * 2 + 1];
                float p = __expf(0.70710678118f * d0);
                den += p;
                o0 = fmaf(p, stqkv[t][2 * SVS + h * 2],     o0);
                o1 = fmaf(p, stqkv[t][2 * SVS + h * 2 + 1], o1);
            }
            float inv = 1.0f / den;
            sttmp[s2][h * 2]     = o0 * inv;
            sttmp[s2][h * 2 + 1] = o1 * inv;
        }
        __syncthreads();

        if (tid < BB) {            // proj + LN1 + FFN + LN2, token-local
            int s2 = tid;
            float cr[SVS];
#pragma unroll
            for (int e = 0; e < SVS; e++) {
                float acc = poB[e];
#pragma unroll
                for (int f = 0; f < SVS; f++) acc = fmaf(sttmp[s2][f], poW[e * SVS + f], acc);
                cr[e] = stx[s2][e] + acc;
            }
            ln_vec<SVS>(cr, pg1, pbe1);
            float hb[FFND];
#pragma unroll
            for (int j = 0; j < FFND; j++) {
                float acc = p1B[j];
#pragma unroll
                for (int e = 0; e < SVS; e++) acc = fmaf(cr[e], p1W[j * SVS + e], acc);
                hb[j] = fmaxf(acc, 0.f);
            }
            float fr[SVS];
#pragma unroll
            for (int e = 0; e < SVS; e++) {
                float acc = p2B[e];
#pragma unroll
                for (int j = 0; j < FFND; j++) acc = fmaf(hb[j], p2W[e * FFND + j], acc);
                fr[e] = cr[e] + acc;
            }
            ln_vec<SVS>(fr, pg2, pbe2);
#pragma unroll
            for (int e = 0; e < SVS; e++) stx[s2][e] = fr[e];
        }
        __syncthreads();
    }

    if (tid < BB * SVS) {
        int b = tid / SVS, o = tid % SVS;
        sec[(size_t)b * (NSEQ * SVS) + (size_t)i * SVS + o] = stx[b][o];
    }
}

__global__ __launch_bounds__(256, 1)
void head_kernel(const float* __restrict__ sec,
                 const float* __restrict__ plW, const float* __restrict__ plb,
                 const float* __restrict__ llW, const float* __restrict__ llb,
                 float* __restrict__ out)
{
    const int b = blockIdx.x, tid = threadIdx.x;
    const float* fb = sec + (size_t)b * (NSEQ * SVS);
    float acc[8];
#pragma unroll
    for (int p = 0; p < 8; p++) acc[p] = 0.f;
    for (int f = tid; f < NSEQ * SVS; f += 256) {
        float xv = fb[f];
#pragma unroll
        for (int p = 0; p < 8; p++)
            acc[p] = fmaf(xv, plW[p * (NSEQ * SVS) + f], acc[p]);
    }
#pragma unroll
    for (int p = 0; p < 8; p++) {
#pragma unroll
        for (int off = 32; off > 0; off >>= 1)
            acc[p] += __shfl_down(acc[p], off, 64);
    }
    __shared__ float red[4][8];
    const int wv = tid >> 6, ln = tid & 63;
    if (ln == 0) {
#pragma unroll
        for (int p = 0; p < 8; p++) red[wv][p] = acc[p];
    }
    __syncthreads();
    if (tid == 0) {
        float s8[8];
#pragma unroll
        for (int p = 0; p < 8; p++)
            s8[p] = red[0][p] + red[1][p] + red[2][p] + red[3][p] + plb[p];
#pragma unroll
        for (int qq = 0; qq < 2; qq++) {
            float o = llb[qq];
#pragma unroll
            for (int p = 0; p < 8; p++) o = fmaf(s8[p], llW[qq * 8 + p], o);
            out[b * 2 + qq] = o;
        }
    }
}

extern "C" void kernel_launch(void* const* d_in, const int* in_sizes, int n_in,
                              void* d_out, int out_size, void* d_ws, size_t ws_size,
                              hipStream_t stream)
{
    const float* X     = (const float*)d_in[0];
    const float* Wqkv  = (const float*)d_in[1];
    const float* bqkv  = (const float*)d_in[2];
    const float* Wo    = (const float*)d_in[3];
    const float* bo    = (const float*)d_in[4];
    const float* W1    = (const float*)d_in[5];
    const float* b1    = (const float*)d_in[6];
    const float* W2    = (const float*)d_in[7];
    const float* b2    = (const float*)d_in[8];
    const float* g1    = (const float*)d_in[9];
    const float* be1   = (const float*)d_in[10];
    const float* g2    = (const float*)d_in[11];
    const float* be2   = (const float*)d_in[12];
    const float* linW  = (const float*)d_in[13];
    const float* linb  = (const float*)d_in[14];
    const float* sWqkv = (const float*)d_in[15];
    const float* sbqkv = (const float*)d_in[16];
    const float* sWo   = (const float*)d_in[17];
    const float* sbo   = (const float*)d_in[18];
    const float* sW1   = (const float*)d_in[19];
    const float* sb1   = (const float*)d_in[20];
    const float* sW2   = (const float*)d_in[21];
    const float* sb2   = (const float*)d_in[22];
    const float* sg1   = (const float*)d_in[23];
    const float* sbe1  = (const float*)d_in[24];
    const float* sg2   = (const float*)d_in[25];
    const float* sbe2  = (const float*)d_in[26];
    const float* plW   = (const float*)d_in[27];
    const float* plb   = (const float*)d_in[28];
    const float* llW   = (const float*)d_in[29];
    const float* llb   = (const float*)d_in[30];

    float* part = (float*)d_ws;                         // 430*7*32*10 fp32 = 3,852,800 B
    float* sec  = part + (size_t)NSEQ * BPI * BB * SVS; // 550,400 B more

    ptenc_kernel<<<NSEQ * BPI, NTA, 0, stream>>>(X, Wqkv, bqkv, Wo, bo, W1, b1, W2, b2,
                                                 g1, be1, g2, be2, linW, part);
    stenc_kernel<<<NSEQ, NTB, 0, stream>>>(part, linb,
                                           sWqkv, sbqkv, sWo, sbo, sW1, sb1, sW2, sb2,
                                           sg1, sbe1, sg2, sbe2, sec);
    head_kernel<<<BB, 256, 0, stream>>>(sec, plW, plb, llW, llb, (float*)d_out);
}